// Round 11
// baseline (36003.619 us; speedup 1.0000x reference)
//
#include <hip/hip_runtime.h>
#include <math.h>

#define RSV   2048
#define NIN   8
#define TT    16384
#define NB    128
#define TB    512
#define RPB   16          // rows per block (8 waves x 2 rows)
#define OUTW  (RSV+NIN)   // 2056

typedef unsigned long long u64;

// ws layout: buf0 = ws[0..2048) u64, buf1 = ws[2048..4096) u64 (32 KiB)
// word = (stamp << 32) | float_bits

__global__ __launch_bounds__(256) void esn_init(const float* __restrict__ h0,
                                                u64* __restrict__ ws) {
    int i = blockIdx.x * blockDim.x + threadIdx.x;
    if (i < RSV) {
        u64 w0 = (u64)__float_as_uint(h0[i]);   // buf0: stamp 0 | h0 payload
        __hip_atomic_store(ws + i,       w0,   __ATOMIC_RELAXED, __HIP_MEMORY_SCOPE_AGENT);
        __hip_atomic_store(ws + RSV + i, 0ull, __ATOMIC_RELAXED, __HIP_MEMORY_SCOPE_AGENT);
    }
}

__device__ __forceinline__ float tanh_fast(float s) {
    return 1.0f - 2.0f / (__expf(2.0f * s) + 1.0f);
}

__device__ __forceinline__ u64 u64min(u64 a, u64 b) { return a < b ? a : b; }

__global__ __launch_bounds__(TB, 2) void esn_main(const float* __restrict__ x,
                                                  const float* __restrict__ h0,
                                                  const float* __restrict__ Win,
                                                  const float* __restrict__ Wh,
                                                  float* __restrict__ out,
                                                  u64* __restrict__ ws) {
    __shared__ __align__(16) float h_lds[2][RSV];   // double-buffered h stage (16 KB)

    const int tid  = threadIdx.x;
    const int b    = blockIdx.x;
    const int wave = tid >> 6;
    const int lane = tid & 63;

    u64* buf0 = ws;
    u64* buf1 = ws + RSV;

    // ---- wave owns rows row0, row0+1; lane owns cols {lane + 64j}, j=0..31 ----
    const int row0 = b * RPB + wave * 2;
    float wh0[32], wh1[32];
    {
        const float* wr0 = Wh + (size_t)(row0 + 0) * RSV + lane;
        const float* wr1 = Wh + (size_t)(row0 + 1) * RSV + lane;
        #pragma unroll
        for (int j = 0; j < 32; ++j) wh0[j] = wr0[64 * j];
        #pragma unroll
        for (int j = 0; j < 32; ++j) wh1[j] = wr1[64 * j];
    }

    const int frow = row0 + (lane & 1);   // finalize lanes 0,1 own one row each
    float hp = (lane < 2) ? h0[frow] : 0.f;

    #pragma unroll 1
    for (int t = 1; t <= TT; ++t) {
        const u64* src = (t & 1) ? buf0 : buf1;   // holds h_{t-1} (stamps t-1)
        u64*       dst = (t & 1) ? buf1 : buf0;   // receives h_t (stamps t)
        float*     hl  = h_lds[t & 1];
        const u64  thr = ((u64)(unsigned)(t - 1)) << 32;   // all-stamps>=t-1 detect

        // ---- h-independent work first (hidden under the poll) ----
        float winx = 0.f;
        if (lane < 2) {
            const float4* wr4 = (const float4*)(Win + frow * NIN);   // L1-hot 32 B
            const float4* xr4 = (const float4*)(x + (size_t)(t - 1) * NIN);
            float4 wa = wr4[0], wb = wr4[1];
            float4 xa = xr4[0], xb = xr4[1];
            winx = wa.x*xa.x + wa.y*xa.y + wa.z*xa.z + wa.w*xa.w
                 + wb.x*xb.x + wb.y*xb.y + wb.z*xb.z + wb.w*xb.w;
        }
        if (b == 0 && wave == 1 && lane < NIN)
            __builtin_nontemporal_store(x[(size_t)(t - 1) * NIN + lane],
                                        &out[(size_t)(t - 1) * OUTW + RSV + lane]);

        // ---- 2-deep pipelined poll of OWN 4 stamped words: while batch A is
        //      being checked (vmcnt(4)), batch B is already in flight -> sample
        //      cadence ~RT/2 instead of RT. min4(u64) >= thr <=> all stamps ok. ----
        const u64* sp = src + tid * 4;
        u64 v0, v1, v2, v3;
        {
            u64 a0 = __hip_atomic_load(sp + 0, __ATOMIC_RELAXED, __HIP_MEMORY_SCOPE_AGENT);
            u64 a1 = __hip_atomic_load(sp + 1, __ATOMIC_RELAXED, __HIP_MEMORY_SCOPE_AGENT);
            u64 a2 = __hip_atomic_load(sp + 2, __ATOMIC_RELAXED, __HIP_MEMORY_SCOPE_AGENT);
            u64 a3 = __hip_atomic_load(sp + 3, __ATOMIC_RELAXED, __HIP_MEMORY_SCOPE_AGENT);
            for (;;) {
                u64 b0 = __hip_atomic_load(sp + 0, __ATOMIC_RELAXED, __HIP_MEMORY_SCOPE_AGENT);
                u64 b1 = __hip_atomic_load(sp + 1, __ATOMIC_RELAXED, __HIP_MEMORY_SCOPE_AGENT);
                u64 b2 = __hip_atomic_load(sp + 2, __ATOMIC_RELAXED, __HIP_MEMORY_SCOPE_AGENT);
                u64 b3 = __hip_atomic_load(sp + 3, __ATOMIC_RELAXED, __HIP_MEMORY_SCOPE_AGENT);
                if (u64min(u64min(a0, a1), u64min(a2, a3)) >= thr) {
                    v0 = a0; v1 = a1; v2 = a2; v3 = a3; break;
                }
                a0 = __hip_atomic_load(sp + 0, __ATOMIC_RELAXED, __HIP_MEMORY_SCOPE_AGENT);
                a1 = __hip_atomic_load(sp + 1, __ATOMIC_RELAXED, __HIP_MEMORY_SCOPE_AGENT);
                a2 = __hip_atomic_load(sp + 2, __ATOMIC_RELAXED, __HIP_MEMORY_SCOPE_AGENT);
                a3 = __hip_atomic_load(sp + 3, __ATOMIC_RELAXED, __HIP_MEMORY_SCOPE_AGENT);
                if (u64min(u64min(b0, b1), u64min(b2, b3)) >= thr) {
                    v0 = b0; v1 = b1; v2 = b2; v3 = b3; break;
                }
            }
        }
        float4 hv4;
        hv4.x = __uint_as_float((unsigned)v0);
        hv4.y = __uint_as_float((unsigned)v1);
        hv4.z = __uint_as_float((unsigned)v2);
        hv4.w = __uint_as_float((unsigned)v3);
        *(float4*)&hl[tid * 4] = hv4;
        __syncthreads();   // the ONLY barrier per step (LDS dbuf => WAR-safe)

        // ---- deferred, coalesced out-write: hl holds h_{t-1}; out row t-2 ----
        if (wave == 0 && lane < RPB && t >= 2)
            __builtin_nontemporal_store(hl[b * RPB + lane],
                                        &out[(size_t)(t - 2) * OUTW + b * RPB + lane]);

        // ---- 2-row matvec, 4-way split accumulators ----
        float pxa0 = 0.f, pxa1 = 0.f, pxa2 = 0.f, pxa3 = 0.f;
        float pya0 = 0.f, pya1 = 0.f, pya2 = 0.f, pya3 = 0.f;
        #pragma unroll
        for (int j = 0; j < 32; j += 4) {
            float h0v = hl[lane + 64 * (j + 0)];
            float h1v = hl[lane + 64 * (j + 1)];
            float h2v = hl[lane + 64 * (j + 2)];
            float h3v = hl[lane + 64 * (j + 3)];
            pxa0 += wh0[j + 0] * h0v;  pya0 += wh1[j + 0] * h0v;
            pxa1 += wh0[j + 1] * h1v;  pya1 += wh1[j + 1] * h1v;
            pxa2 += wh0[j + 2] * h2v;  pya2 += wh1[j + 2] * h2v;
            pxa3 += wh0[j + 3] * h3v;  pya3 += wh1[j + 3] * h3v;
        }
        float px = (pxa0 + pxa1) + (pxa2 + pxa3);
        float py = (pya0 + pya1) + (pya2 + pya3);

        // ---- packed butterfly: 6 shuffles for both rows ----
        float q = (lane & 1) ? py : px;
        float r = (lane & 1) ? px : py;
        q += __shfl_xor(r, 1);
        #pragma unroll
        for (int m = 2; m <= 32; m <<= 1)
            q += __shfl_xor(q, m);             // lane0: sum row0, lane1: sum row0+1

        // ---- finalize lanes publish; stamp+payload single 8B store ----
        if (lane < 2) {
            float s  = q + winx;
            float ht = 0.9f * hp + 0.1f * tanh_fast(s);
            hp = ht;
            u64 pk = ((u64)(unsigned)t << 32) | (u64)__float_as_uint(ht);
            __hip_atomic_store(dst + frow, pk, __ATOMIC_RELAXED, __HIP_MEMORY_SCOPE_AGENT);
        }
    }

    // ---- epilogue: last out row (TT-1) = h_TT, from finalize registers ----
    if (lane < 2)
        __builtin_nontemporal_store(hp, &out[(size_t)(TT - 1) * OUTW + frow]);
}

extern "C" void kernel_launch(void* const* d_in, const int* in_sizes, int n_in,
                              void* d_out, int out_size, void* d_ws, size_t ws_size,
                              hipStream_t stream) {
    const float* x   = (const float*)d_in[0];
    const float* h0  = (const float*)d_in[1];
    const float* Win = (const float*)d_in[2];
    const float* Wh  = (const float*)d_in[3];
    float* out = (float*)d_out;
    u64*   ws  = (u64*)d_ws;

    hipLaunchKernelGGL(esn_init, dim3(8), dim3(256), 0, stream, h0, ws);
    hipLaunchKernelGGL(esn_main, dim3(NB), dim3(TB), 0, stream,
                       x, h0, Win, Wh, out, ws);
}

// Round 12
// 28252.307 us; speedup vs baseline: 1.2744x; 1.2744x over previous
//
#include <hip/hip_runtime.h>
#include <math.h>

#define RSV   2048
#define NIN   8
#define TT    16384
#define NB    128
#define TB    512
#define RPB   16          // rows per block (8 waves x 2 rows)
#define OUTW  (RSV+NIN)   // 2056

typedef unsigned long long u64;

// ws layout: buf0 = ws[0..2048) u64, buf1 = ws[2048..4096) u64 (32 KiB)
// word = (stamp << 32) | float_bits

__global__ __launch_bounds__(256) void esn_init(const float* __restrict__ h0,
                                                u64* __restrict__ ws) {
    int i = blockIdx.x * blockDim.x + threadIdx.x;
    if (i < RSV) {
        u64 w0 = (u64)__float_as_uint(h0[i]);   // buf0: stamp 0 | h0 payload
        __hip_atomic_store(ws + i,       w0,   __ATOMIC_RELAXED, __HIP_MEMORY_SCOPE_AGENT);
        __hip_atomic_store(ws + RSV + i, 0ull, __ATOMIC_RELAXED, __HIP_MEMORY_SCOPE_AGENT);
    }
}

__device__ __forceinline__ float tanh_fast(float s) {
    return 1.0f - 2.0f / (__expf(2.0f * s) + 1.0f);
}

__global__ __launch_bounds__(TB, 2) void esn_main(const float* __restrict__ x,
                                                  const float* __restrict__ h0,
                                                  const float* __restrict__ Win,
                                                  const float* __restrict__ Wh,
                                                  float* __restrict__ out,
                                                  u64* __restrict__ ws) {
    __shared__ __align__(16) float h_lds[2][RSV];   // double-buffered h stage (16 KB)

    const int tid  = threadIdx.x;
    const int b    = blockIdx.x;
    const int wave = tid >> 6;
    const int lane = tid & 63;

    u64* buf0 = ws;
    u64* buf1 = ws + RSV;

    // ---- wave owns rows row0, row0+1; lane owns cols {lane + 64j}, j=0..31.
    //      Loop-invariant addresses: compiler sinks these into the t-loop as
    //      L2-hit loads overlapped with the poll window (R6-verified OK). ----
    const int row0 = b * RPB + wave * 2;
    float wh0[32], wh1[32];
    {
        const float* wr0 = Wh + (size_t)(row0 + 0) * RSV + lane;
        const float* wr1 = Wh + (size_t)(row0 + 1) * RSV + lane;
        #pragma unroll
        for (int j = 0; j < 32; ++j) wh0[j] = wr0[64 * j];
        #pragma unroll
        for (int j = 0; j < 32; ++j) wh1[j] = wr1[64 * j];
    }

    const int frow = row0 + (lane & 1);   // finalize lanes 0,1 own one row each
    float hp = (lane < 2) ? h0[frow] : 0.f;

    #pragma unroll 1
    for (int t = 1; t <= TT; ++t) {
        const u64* src = (t & 1) ? buf0 : buf1;   // holds h_{t-1} (stamps t-1)
        u64*       dst = (t & 1) ? buf1 : buf0;   // receives h_t (stamps t)
        float*     hl  = h_lds[t & 1];
        const unsigned want = (unsigned)(t - 1);

        // ---- h-independent work first (hidden under the poll) ----
        float winx = 0.f;
        if (lane < 2) {
            const float4* wr4 = (const float4*)(Win + frow * NIN);   // L1-hot 32 B
            const float4* xr4 = (const float4*)(x + (size_t)(t - 1) * NIN);
            float4 wa = wr4[0], wb = wr4[1];
            float4 xa = xr4[0], xb = xr4[1];
            winx = wa.x*xa.x + wa.y*xa.y + wa.z*xa.z + wa.w*xa.w
                 + wb.x*xb.x + wb.y*xb.y + wb.z*xb.z + wb.w*xb.w;
        }
        if (b == 0 && wave == 1 && lane < NIN)
            __builtin_nontemporal_store(x[(size_t)(t - 1) * NIN + lane],
                                        &out[(size_t)(t - 1) * OUTW + RSV + lane]);

        // ---- tight poll of OWN 4 stamped words (block covers all 2048) ----
        const u64* sp = src + tid * 4;
        u64 v0, v1, v2, v3;
        for (;;) {
            v0 = __hip_atomic_load(sp + 0, __ATOMIC_RELAXED, __HIP_MEMORY_SCOPE_AGENT);
            v1 = __hip_atomic_load(sp + 1, __ATOMIC_RELAXED, __HIP_MEMORY_SCOPE_AGENT);
            v2 = __hip_atomic_load(sp + 2, __ATOMIC_RELAXED, __HIP_MEMORY_SCOPE_AGENT);
            v3 = __hip_atomic_load(sp + 3, __ATOMIC_RELAXED, __HIP_MEMORY_SCOPE_AGENT);
            if ((unsigned)(v0 >> 32) >= want && (unsigned)(v1 >> 32) >= want &&
                (unsigned)(v2 >> 32) >= want && (unsigned)(v3 >> 32) >= want) break;
        }
        float4 hv4;
        hv4.x = __uint_as_float((unsigned)v0);
        hv4.y = __uint_as_float((unsigned)v1);
        hv4.z = __uint_as_float((unsigned)v2);
        hv4.w = __uint_as_float((unsigned)v3);
        *(float4*)&hl[tid * 4] = hv4;
        __syncthreads();   // the ONLY barrier per step (LDS dbuf => WAR-safe)

        // ---- deferred, coalesced out-write: hl holds h_{t-1}; out row t-2 ----
        if (wave == 0 && lane < RPB && t >= 2)
            __builtin_nontemporal_store(hl[b * RPB + lane],
                                        &out[(size_t)(t - 2) * OUTW + b * RPB + lane]);

        // ---- 2-row matvec, 4-way split accumulators ----
        float pxa0 = 0.f, pxa1 = 0.f, pxa2 = 0.f, pxa3 = 0.f;
        float pya0 = 0.f, pya1 = 0.f, pya2 = 0.f, pya3 = 0.f;
        #pragma unroll
        for (int j = 0; j < 32; j += 4) {
            float h0v = hl[lane + 64 * (j + 0)];
            float h1v = hl[lane + 64 * (j + 1)];
            float h2v = hl[lane + 64 * (j + 2)];
            float h3v = hl[lane + 64 * (j + 3)];
            pxa0 += wh0[j + 0] * h0v;  pya0 += wh1[j + 0] * h0v;
            pxa1 += wh0[j + 1] * h1v;  pya1 += wh1[j + 1] * h1v;
            pxa2 += wh0[j + 2] * h2v;  pya2 += wh1[j + 2] * h2v;
            pxa3 += wh0[j + 3] * h3v;  pya3 += wh1[j + 3] * h3v;
        }
        float px = (pxa0 + pxa1) + (pxa2 + pxa3);
        float py = (pya0 + pya1) + (pya2 + pya3);

        // ---- packed butterfly: 6 shuffles for both rows ----
        float q = (lane & 1) ? py : px;
        float r = (lane & 1) ? px : py;
        q += __shfl_xor(r, 1);
        #pragma unroll
        for (int m = 2; m <= 32; m <<= 1)
            q += __shfl_xor(q, m);             // lane0: sum row0, lane1: sum row0+1

        // ---- finalize lanes publish; stamp+payload single 8B store ----
        if (lane < 2) {
            float s  = q + winx;
            float ht = 0.9f * hp + 0.1f * tanh_fast(s);
            hp = ht;
            u64 pk = ((u64)(unsigned)t << 32) | (u64)__float_as_uint(ht);
            __hip_atomic_store(dst + frow, pk, __ATOMIC_RELAXED, __HIP_MEMORY_SCOPE_AGENT);
        }
    }

    // ---- epilogue: last out row (TT-1) = h_TT, from finalize registers ----
    if (lane < 2)
        __builtin_nontemporal_store(hp, &out[(size_t)(TT - 1) * OUTW + frow]);
}

extern "C" void kernel_launch(void* const* d_in, const int* in_sizes, int n_in,
                              void* d_out, int out_size, void* d_ws, size_t ws_size,
                              hipStream_t stream) {
    const float* x   = (const float*)d_in[0];
    const float* h0  = (const float*)d_in[1];
    const float* Win = (const float*)d_in[2];
    const float* Wh  = (const float*)d_in[3];
    float* out = (float*)d_out;
    u64*   ws  = (u64*)d_ws;

    hipLaunchKernelGGL(esn_init, dim3(8), dim3(256), 0, stream, h0, ws);
    hipLaunchKernelGGL(esn_main, dim3(NB), dim3(TB), 0, stream,
                       x, h0, Win, Wh, out, ws);
}

// Round 13
// 27941.110 us; speedup vs baseline: 1.2886x; 1.0111x over previous
//
#include <hip/hip_runtime.h>
#include <math.h>

#define RSV   2048
#define NIN   8
#define TT    16384
#define NB    128
#define TB    512
#define RPB   16          // rows per block (8 waves x 2 rows)
#define OUTW  (RSV+NIN)   // 2056

typedef unsigned long long u64;

// ws layout: buf0 = ws[0..2048) u64, buf1 = ws[2048..4096) u64 (32 KiB)
// word = (stamp << 32) | float_bits

__global__ __launch_bounds__(256) void esn_init(const float* __restrict__ h0,
                                                u64* __restrict__ ws) {
    int i = blockIdx.x * blockDim.x + threadIdx.x;
    if (i < RSV) {
        u64 w0 = (u64)__float_as_uint(h0[i]);   // buf0: stamp 0 | h0 payload
        __hip_atomic_store(ws + i,       w0,   __ATOMIC_RELAXED, __HIP_MEMORY_SCOPE_AGENT);
        __hip_atomic_store(ws + RSV + i, 0ull, __ATOMIC_RELAXED, __HIP_MEMORY_SCOPE_AGENT);
    }
}

__device__ __forceinline__ float tanh_fast(float s) {
    return 1.0f - 2.0f / (__expf(2.0f * s) + 1.0f);
}

__global__ __launch_bounds__(TB, 2) void esn_main(const float* __restrict__ x,
                                                  const float* __restrict__ h0,
                                                  const float* __restrict__ Win,
                                                  const float* __restrict__ Wh,
                                                  float* __restrict__ out,
                                                  u64* __restrict__ ws) {
    __shared__ __align__(16) float h_lds[2][RSV];   // double-buffered h stage (16 KB)

    const int tid  = threadIdx.x;
    const int b    = blockIdx.x;
    const int wave = tid >> 6;
    const int lane = tid & 63;

    u64* buf0 = ws;
    u64* buf1 = ws + RSV;

    // ---- wave owns rows row0, row0+1; lane owns cols {4*lane + 256j + k},
    //      j=0..7, k=0..3 -> LDS reads become 8 x ds_read_b128, address
    //      pattern identical to the (0-conflict) staging write. One-time
    //      weight loads are float4-contiguous per lane (perfectly coalesced:
    //      64 lanes x 16 B = 1 KB per j). ----
    const int row0 = b * RPB + wave * 2;
    float4 wA[8], wB[8];
    {
        const float* wr0 = Wh + (size_t)(row0 + 0) * RSV + 4 * lane;
        const float* wr1 = Wh + (size_t)(row0 + 1) * RSV + 4 * lane;
        #pragma unroll
        for (int j = 0; j < 8; ++j) {
            wA[j] = *(const float4*)(wr0 + 256 * j);
            wB[j] = *(const float4*)(wr1 + 256 * j);
        }
    }

    const int frow = row0 + (lane & 1);   // finalize lanes 0,1 own one row each
    float hp = (lane < 2) ? h0[frow] : 0.f;

    #pragma unroll 1
    for (int t = 1; t <= TT; ++t) {
        const u64* src = (t & 1) ? buf0 : buf1;   // holds h_{t-1} (stamps t-1)
        u64*       dst = (t & 1) ? buf1 : buf0;   // receives h_t (stamps t)
        float*     hl  = h_lds[t & 1];
        const unsigned want = (unsigned)(t - 1);

        // ---- h-independent work first (hidden under the poll) ----
        float winx = 0.f;
        if (lane < 2) {
            const float4* wr4 = (const float4*)(Win + frow * NIN);   // L1-hot 32 B
            const float4* xr4 = (const float4*)(x + (size_t)(t - 1) * NIN);
            float4 wa = wr4[0], wb = wr4[1];
            float4 xa = xr4[0], xb = xr4[1];
            winx = wa.x*xa.x + wa.y*xa.y + wa.z*xa.z + wa.w*xa.w
                 + wb.x*xb.x + wb.y*xb.y + wb.z*xb.z + wb.w*xb.w;
        }
        if (b == 0 && wave == 1 && lane < NIN)
            __builtin_nontemporal_store(x[(size_t)(t - 1) * NIN + lane],
                                        &out[(size_t)(t - 1) * OUTW + RSV + lane]);

        // ---- tight poll of OWN 4 stamped words (block covers all 2048) ----
        const u64* sp = src + tid * 4;
        u64 v0, v1, v2, v3;
        for (;;) {
            v0 = __hip_atomic_load(sp + 0, __ATOMIC_RELAXED, __HIP_MEMORY_SCOPE_AGENT);
            v1 = __hip_atomic_load(sp + 1, __ATOMIC_RELAXED, __HIP_MEMORY_SCOPE_AGENT);
            v2 = __hip_atomic_load(sp + 2, __ATOMIC_RELAXED, __HIP_MEMORY_SCOPE_AGENT);
            v3 = __hip_atomic_load(sp + 3, __ATOMIC_RELAXED, __HIP_MEMORY_SCOPE_AGENT);
            if ((unsigned)(v0 >> 32) >= want && (unsigned)(v1 >> 32) >= want &&
                (unsigned)(v2 >> 32) >= want && (unsigned)(v3 >> 32) >= want) break;
        }
        float4 hv4;
        hv4.x = __uint_as_float((unsigned)v0);
        hv4.y = __uint_as_float((unsigned)v1);
        hv4.z = __uint_as_float((unsigned)v2);
        hv4.w = __uint_as_float((unsigned)v3);
        *(float4*)&hl[tid * 4] = hv4;
        __syncthreads();   // the ONLY barrier per step (LDS dbuf => WAR-safe)

        // ---- 2-row matvec: 8 x ds_read_b128, split accumulators ----
        const float4* hl4 = (const float4*)hl;
        float px0 = 0.f, px1 = 0.f, py0 = 0.f, py1 = 0.f;
        #pragma unroll
        for (int j = 0; j < 8; j += 2) {
            float4 ha = hl4[lane + 64 * (j + 0)];
            float4 hb = hl4[lane + 64 * (j + 1)];
            px0 += wA[j].x*ha.x + wA[j].y*ha.y + wA[j].z*ha.z + wA[j].w*ha.w;
            py0 += wB[j].x*ha.x + wB[j].y*ha.y + wB[j].z*ha.z + wB[j].w*ha.w;
            px1 += wA[j+1].x*hb.x + wA[j+1].y*hb.y + wA[j+1].z*hb.z + wA[j+1].w*hb.w;
            py1 += wB[j+1].x*hb.x + wB[j+1].y*hb.y + wB[j+1].z*hb.z + wB[j+1].w*hb.w;
        }
        float px = px0 + px1;
        float py = py0 + py1;

        // ---- packed butterfly: 6 shuffles for both rows ----
        float q = (lane & 1) ? py : px;
        float r = (lane & 1) ? px : py;
        q += __shfl_xor(r, 1);
        #pragma unroll
        for (int m = 2; m <= 32; m <<= 1)
            q += __shfl_xor(q, m);             // lane0: sum row0, lane1: sum row0+1

        // ---- finalize lanes publish FIRST (unblocks the grid) ----
        if (lane < 2) {
            float s  = q + winx;
            float ht = 0.9f * hp + 0.1f * tanh_fast(s);
            hp = ht;
            u64 pk = ((u64)(unsigned)t << 32) | (u64)__float_as_uint(ht);
            __hip_atomic_store(dst + frow, pk, __ATOMIC_RELAXED, __HIP_MEMORY_SCOPE_AGENT);
        }

        // ---- deferred, coalesced out-write AFTER publish: hl (valid until the
        //      t+2 stage) holds h_{t-1}; out row t-2 slice = one 64 B nt store ----
        if (wave == 0 && lane < RPB && t >= 2)
            __builtin_nontemporal_store(hl[b * RPB + lane],
                                        &out[(size_t)(t - 2) * OUTW + b * RPB + lane]);
    }

    // ---- epilogue: last out row (TT-1) = h_TT, from finalize registers ----
    if (lane < 2)
        __builtin_nontemporal_store(hp, &out[(size_t)(TT - 1) * OUTW + frow]);
}

extern "C" void kernel_launch(void* const* d_in, const int* in_sizes, int n_in,
                              void* d_out, int out_size, void* d_ws, size_t ws_size,
                              hipStream_t stream) {
    const float* x   = (const float*)d_in[0];
    const float* h0  = (const float*)d_in[1];
    const float* Win = (const float*)d_in[2];
    const float* Wh  = (const float*)d_in[3];
    float* out = (float*)d_out;
    u64*   ws  = (u64*)d_ws;

    hipLaunchKernelGGL(esn_init, dim3(8), dim3(256), 0, stream, h0, ws);
    hipLaunchKernelGGL(esn_main, dim3(NB), dim3(TB), 0, stream,
                       x, h0, Win, Wh, out, ws);
}